// Round 1
// baseline (964.285 us; speedup 1.0000x reference)
//
#include <hip/hip_runtime.h>
#include <hip/hip_bf16.h>
#include <stdint.h>

#define DIM   1024
#define NE    8
#define HID   2730
#define HPAD  2752      // pad K of stage-2 to multiple of 64
#define NTOK  8192      // B*N = 4*2048
#define CAP   8192      // max tokens per expert (top-2 distinct => <= NTOK)

typedef __bf16 bf16x8 __attribute__((ext_vector_type(8)));
typedef float  floatx4 __attribute__((ext_vector_type(4)));

__device__ __forceinline__ unsigned short f2bf(float f) {
    union { float f; unsigned int u; } v; v.f = f;
    unsigned int u = v.u;
    unsigned int r = (u + 0x7fffu + ((u >> 16) & 1u)) >> 16;  // RNE
    return (unsigned short)r;
}

__device__ __forceinline__ void gl2lds16(const void* g, void* l) {
    __builtin_amdgcn_global_load_lds((const __attribute__((address_space(1))) void*)g,
                                     (__attribute__((address_space(3))) void*)l,
                                     16, 0, 0);
}

// ---------------- conversions ----------------
__global__ void convert_x_kernel(const float* __restrict__ x, unsigned short* __restrict__ xb) {
    int i = blockIdx.x * 256 + threadIdx.x;            // 2,097,152 float4 chunks
    float4 v = ((const float4*)x)[i];
    uint2 o;
    o.x = (unsigned)f2bf(v.x) | ((unsigned)f2bf(v.y) << 16);
    o.y = (unsigned)f2bf(v.z) | ((unsigned)f2bf(v.w) << 16);
    *(uint2*)(xb + i * 4) = o;
}

__global__ void convert_w13_kernel(const float* __restrict__ w1, const float* __restrict__ w3,
                                   unsigned short* __restrict__ w1b, unsigned short* __restrict__ w3b) {
    const int HALF = (NE * HID * DIM) / 4;             // 5,591,040
    int i = blockIdx.x * 256 + threadIdx.x;
    const float* src; unsigned short* dst; int j;
    if (i < HALF) { src = w1; dst = w1b; j = i; }
    else          { src = w3; dst = w3b; j = i - HALF; }
    float4 v = ((const float4*)src)[j];
    uint2 o;
    o.x = (unsigned)f2bf(v.x) | ((unsigned)f2bf(v.y) << 16);
    o.y = (unsigned)f2bf(v.z) | ((unsigned)f2bf(v.w) << 16);
    *(uint2*)(dst + (size_t)j * 4) = o;
}

__global__ void convert_w2_kernel(const float* __restrict__ w2, unsigned short* __restrict__ w2b) {
    int i = blockIdx.x * 256 + threadIdx.x;            // 8192 rows * 688 chunks
    int r = i / 688;
    int c = (i - r * 688) * 4;
    const float* src = w2 + r * HID;
    unsigned short q[4];
#pragma unroll
    for (int j = 0; j < 4; ++j) {
        int col = c + j;
        q[j] = (col < HID) ? f2bf(src[col]) : (unsigned short)0;  // zero pad => garbage h pad cols annihilate
    }
    uint2 o;
    o.x = (unsigned)q[0] | ((unsigned)q[1] << 16);
    o.y = (unsigned)q[2] | ((unsigned)q[3] << 16);
    *(uint2*)(w2b + (size_t)r * HPAD + c) = o;
}

// ---------------- router ----------------
__global__ void router_kernel(const float* __restrict__ x, const float* __restrict__ gw,
                              int* __restrict__ toks, float* __restrict__ wts,
                              int* __restrict__ counts, float* __restrict__ psum) {
    __shared__ float gws[NE * DIM];        // 32 KB
    __shared__ float pblk[4][NE];
    int t = threadIdx.x;
    for (int i = t; i < NE * DIM; i += 256) gws[i] = gw[i];
    __syncthreads();

    int wv = t >> 6, lane = t & 63;
    int tok = blockIdx.x * 4 + wv;
    const float4* x4 = (const float4*)(x + (size_t)tok * DIM);

    float p[NE];
#pragma unroll
    for (int e = 0; e < NE; ++e) p[e] = 0.f;
#pragma unroll
    for (int c = 0; c < 4; ++c) {
        float4 xv = x4[c * 64 + lane];
#pragma unroll
        for (int e = 0; e < NE; ++e) {
            float4 gv = ((const float4*)(gws + e * DIM))[c * 64 + lane];
            p[e] += xv.x * gv.x + xv.y * gv.y + xv.z * gv.z + xv.w * gv.w;
        }
    }
#pragma unroll
    for (int e = 0; e < NE; ++e)
#pragma unroll
        for (int s = 32; s; s >>= 1) p[e] += __shfl_xor(p[e], s, 64);

    if (lane == 0) {
        float mx = p[0];
#pragma unroll
        for (int e = 1; e < NE; ++e) mx = fmaxf(mx, p[e]);
        float ex[NE], s = 0.f;
#pragma unroll
        for (int e = 0; e < NE; ++e) { ex[e] = __expf(p[e] - mx); s += ex[e]; }
        float inv = 1.f / s;
        int i1 = 0, i2 = 0; float v1 = -1.f, v2 = -1.f;
#pragma unroll
        for (int e = 0; e < NE; ++e) {
            float pe = ex[e] * inv;
            pblk[wv][e] = pe;
            if (pe > v1)      { v2 = v1; i2 = i1; v1 = pe; i1 = e; }
            else if (pe > v2) { v2 = pe; i2 = e; }
        }
        float wn = 1.f / (v1 + v2);
        int p1 = atomicAdd(&counts[i1], 1);
        toks[i1 * CAP + p1] = tok; wts[i1 * CAP + p1] = v1 * wn;
        int p2 = atomicAdd(&counts[i2], 1);
        toks[i2 * CAP + p2] = tok; wts[i2 * CAP + p2] = v2 * wn;
    }
    __syncthreads();
    if (t < NE) {
        float s = pblk[0][t] + pblk[1][t] + pblk[2][t] + pblk[3][t];
        atomicAdd(&psum[t], s);
    }
}

__global__ void finalize_kernel(const int* __restrict__ counts, int* __restrict__ offs,
                                const float* __restrict__ psum, float* __restrict__ aux_out) {
    if (threadIdx.x == 0) {
        int off = 0;
        for (int e = 0; e < NE; ++e) { offs[e] = off; off += counts[e]; }
        float s = 0.f;
        for (int e = 0; e < NE; ++e) {
            float d = psum[e] * (1.f / NTOK) - (1.f / NE);
            s += d * d;
        }
        aux_out[0] = 0.01f * s * (1.f / NE);
    }
}

// ---------------- stage-1: h = silu(x@w1^T) * (x@w3^T), gathered rows ----------------
__global__ __launch_bounds__(256, 2) void gemm1_kernel(
    const unsigned short* __restrict__ xb,
    const unsigned short* __restrict__ w1b,
    const unsigned short* __restrict__ w3b,
    unsigned short* __restrict__ h,
    const int* __restrict__ counts, const int* __restrict__ offs,
    const int* __restrict__ toks) {
    const int e = blockIdx.z;
    const int M = counts[e];
    const int m0 = blockIdx.y * 128;
    if (m0 >= M) return;
    const int n0 = blockIdx.x * 128;

    __shared__ unsigned short As[128 * 64];
    __shared__ unsigned short B1s[128 * 64];
    __shared__ unsigned short B3s[128 * 64];

    const int t = threadIdx.x;
    const int rb = t >> 3;            // staged row within 32-row group
    const int kc = (t & 7) * 8;       // k-chunk element offset
    const int* tl = toks + e * CAP;
    int arow[4], brow[4];
#pragma unroll
    for (int i = 0; i < 4; ++i) {
        arow[i] = tl[min(m0 + rb + i * 32, M - 1)];
        brow[i] = min(n0 + rb + i * 32, HID - 1);   // clamp: garbage beyond 2730 is masked downstream
    }
    const unsigned short* w1e = w1b + (size_t)e * HID * DIM;
    const unsigned short* w3e = w3b + (size_t)e * HID * DIM;

    floatx4 acc1[4][4], acc3[4][4];
#pragma unroll
    for (int a = 0; a < 4; ++a)
#pragma unroll
        for (int b = 0; b < 4; ++b) {
            acc1[a][b] = (floatx4){0.f, 0.f, 0.f, 0.f};
            acc3[a][b] = (floatx4){0.f, 0.f, 0.f, 0.f};
        }

    const int wv = t >> 6, lane = t & 63;
    const int wm = (wv & 1) * 64, wn = (wv >> 1) * 64;
    const int lr = lane & 15, lq = lane >> 4;

    for (int k0 = 0; k0 < DIM; k0 += 64) {
#pragma unroll
        for (int i = 0; i < 4; ++i) {
            const int ldso = (i * 256 + t) * 8;
            gl2lds16(xb + (size_t)arow[i] * DIM + k0 + kc, &As[ldso]);
            gl2lds16(w1e + (size_t)brow[i] * DIM + k0 + kc, &B1s[ldso]);
            gl2lds16(w3e + (size_t)brow[i] * DIM + k0 + kc, &B3s[ldso]);
        }
        __syncthreads();
#pragma unroll
        for (int kk = 0; kk < 64; kk += 32) {
            bf16x8 af[4];
#pragma unroll
            for (int mi = 0; mi < 4; ++mi)
                af[mi] = *(const bf16x8*)&As[(wm + mi * 16 + lr) * 64 + kk + lq * 8];
#pragma unroll
            for (int ni = 0; ni < 4; ++ni) {
                bf16x8 b1 = *(const bf16x8*)&B1s[(wn + ni * 16 + lr) * 64 + kk + lq * 8];
                bf16x8 b3 = *(const bf16x8*)&B3s[(wn + ni * 16 + lr) * 64 + kk + lq * 8];
#pragma unroll
                for (int mi = 0; mi < 4; ++mi) {
                    acc1[mi][ni] = __builtin_amdgcn_mfma_f32_16x16x32_bf16(af[mi], b1, acc1[mi][ni], 0, 0, 0);
                    acc3[mi][ni] = __builtin_amdgcn_mfma_f32_16x16x32_bf16(af[mi], b3, acc3[mi][ni], 0, 0, 0);
                }
            }
        }
        __syncthreads();
    }

    const int hb = offs[e];
#pragma unroll
    for (int mi = 0; mi < 4; ++mi) {
#pragma unroll
        for (int rg = 0; rg < 4; ++rg) {
            const int gm = m0 + wm + mi * 16 + lq * 4 + rg;
            if (gm >= M) continue;
            unsigned short* hrow = h + (size_t)(hb + gm) * HPAD;
#pragma unroll
            for (int ni = 0; ni < 4; ++ni) {
                const int col = n0 + wn + ni * 16 + lr;
                if (col >= HPAD) continue;
                float z1 = acc1[mi][ni][rg];
                float z3 = acc3[mi][ni][rg];
                float hv = z1 / (1.f + __expf(-z1)) * z3;   // silu(z1)*z3
                hrow[col] = f2bf(hv);
            }
        }
    }
}

// ---------------- stage-2: out[tok] += wt * (h @ w2^T) ----------------
__global__ __launch_bounds__(256, 2) void gemm2_kernel(
    const unsigned short* __restrict__ h,
    const unsigned short* __restrict__ w2b,
    float* __restrict__ out,
    const int* __restrict__ counts, const int* __restrict__ offs,
    const int* __restrict__ toks, const float* __restrict__ wts) {
    const int e = blockIdx.z;
    const int M = counts[e];
    const int m0 = blockIdx.y * 128;
    if (m0 >= M) return;
    const int n0 = blockIdx.x * 128;

    __shared__ unsigned short As[128 * 64];
    __shared__ unsigned short Bs[128 * 64];

    const int t = threadIdx.x;
    const int rb = t >> 3;
    const int kc = (t & 7) * 8;
    const int hb = offs[e];
    int arow[4], brow[4];
#pragma unroll
    for (int i = 0; i < 4; ++i) {
        arow[i] = hb + min(m0 + rb + i * 32, M - 1);
        brow[i] = n0 + rb + i * 32;              // always < 1024
    }
    const unsigned short* w2e = w2b + (size_t)e * DIM * HPAD;

    floatx4 acc[4][4];
#pragma unroll
    for (int a = 0; a < 4; ++a)
#pragma unroll
        for (int b = 0; b < 4; ++b) acc[a][b] = (floatx4){0.f, 0.f, 0.f, 0.f};

    const int wv = t >> 6, lane = t & 63;
    const int wm = (wv & 1) * 64, wn = (wv >> 1) * 64;
    const int lr = lane & 15, lq = lane >> 4;

    for (int k0 = 0; k0 < HPAD; k0 += 64) {
#pragma unroll
        for (int i = 0; i < 4; ++i) {
            const int ldso = (i * 256 + t) * 8;
            gl2lds16(h + (size_t)arow[i] * HPAD + k0 + kc, &As[ldso]);
            gl2lds16(w2e + (size_t)brow[i] * HPAD + k0 + kc, &Bs[ldso]);
        }
        __syncthreads();
#pragma unroll
        for (int kk = 0; kk < 64; kk += 32) {
            bf16x8 af[4];
#pragma unroll
            for (int mi = 0; mi < 4; ++mi)
                af[mi] = *(const bf16x8*)&As[(wm + mi * 16 + lr) * 64 + kk + lq * 8];
#pragma unroll
            for (int ni = 0; ni < 4; ++ni) {
                bf16x8 bf = *(const bf16x8*)&Bs[(wn + ni * 16 + lr) * 64 + kk + lq * 8];
#pragma unroll
                for (int mi = 0; mi < 4; ++mi)
                    acc[mi][ni] = __builtin_amdgcn_mfma_f32_16x16x32_bf16(af[mi], bf, acc[mi][ni], 0, 0, 0);
            }
        }
        __syncthreads();
    }

#pragma unroll
    for (int mi = 0; mi < 4; ++mi) {
#pragma unroll
        for (int rg = 0; rg < 4; ++rg) {
            const int gm = m0 + wm + mi * 16 + lq * 4 + rg;
            if (gm >= M) continue;
            const int sl = e * CAP + gm;
            const int tok = toks[sl];
            const float wt = wts[sl];
            float* orow = out + (size_t)tok * DIM;
#pragma unroll
            for (int ni = 0; ni < 4; ++ni) {
                const int col = n0 + wn + ni * 16 + lr;
                atomicAdd(&orow[col], wt * acc[mi][ni][rg]);
            }
        }
    }
}

extern "C" void kernel_launch(void* const* d_in, const int* in_sizes, int n_in,
                              void* d_out, int out_size, void* d_ws, size_t ws_size,
                              hipStream_t stream) {
    const float* x  = (const float*)d_in[0];
    const float* gw = (const float*)d_in[1];
    const float* w1 = (const float*)d_in[2];
    const float* w2 = (const float*)d_in[3];   // note: dict order is w1, w2, w3
    const float* w3 = (const float*)d_in[4];
    float* out = (float*)d_out;

    char* ws = (char*)d_ws;
    size_t o = 0;
    auto alloc = [&](size_t bytes) -> void* {
        void* p = ws + o;
        o += (bytes + 255) & ~(size_t)255;
        return p;
    };
    unsigned short* xb   = (unsigned short*)alloc((size_t)NTOK * DIM * 2);
    unsigned short* w1b  = (unsigned short*)alloc((size_t)NE * HID * DIM * 2);
    unsigned short* w3b  = (unsigned short*)alloc((size_t)NE * HID * DIM * 2);
    unsigned short* w2b  = (unsigned short*)alloc((size_t)NE * DIM * HPAD * 2);
    unsigned short* hbuf = (unsigned short*)alloc((size_t)2 * NTOK * HPAD * 2);
    int*   toks   = (int*)alloc((size_t)NE * CAP * 4);
    float* wts    = (float*)alloc((size_t)NE * CAP * 4);
    int*   counts = (int*)alloc(256);
    float* psum   = (float*)alloc(256);
    int*   offs   = (int*)alloc(256);
    if (o > ws_size) return;   // workspace too small: fail loudly via poisoned output

    hipMemsetAsync(d_out, 0, (size_t)out_size * 4, stream);
    hipMemsetAsync(counts, 0, 256, stream);
    hipMemsetAsync(psum, 0, 256, stream);

    convert_x_kernel<<<8192, 256, 0, stream>>>(x, xb);
    convert_w13_kernel<<<43680, 256, 0, stream>>>(w1, w3, w1b, w3b);
    convert_w2_kernel<<<22016, 256, 0, stream>>>(w2, w2b);
    router_kernel<<<2048, 256, 0, stream>>>(x, gw, toks, wts, counts, psum);
    finalize_kernel<<<1, 64, 0, stream>>>(counts, offs, psum, out + (size_t)NTOK * DIM);
    gemm1_kernel<<<dim3(22, 64, 8), 256, 0, stream>>>(xb, w1b, w3b, hbuf, counts, offs, toks);
    gemm2_kernel<<<dim3(8, 64, 8), 256, 0, stream>>>(hbuf, w2b, out, counts, offs, toks, wts);
}

// Round 2
// 899.644 us; speedup vs baseline: 1.0719x; 1.0719x over previous
//
#include <hip/hip_runtime.h>
#include <hip/hip_bf16.h>
#include <stdint.h>

#define DIM   1024
#define NE    8
#define HID   2730
#define HPAD  2752      // pad K of stage-2 to multiple of 64
#define NTOK  8192      // B*N = 4*2048
#define CAP   8192      // max tokens per expert

typedef __bf16 bf16x8 __attribute__((ext_vector_type(8)));
typedef float  floatx4 __attribute__((ext_vector_type(4)));

__device__ __forceinline__ unsigned short f2bf(float f) {
    union { float f; unsigned int u; } v; v.f = f;
    unsigned int u = v.u;
    unsigned int r = (u + 0x7fffu + ((u >> 16) & 1u)) >> 16;  // RNE
    return (unsigned short)r;
}

__device__ __forceinline__ void gl2lds16(const void* g, void* l) {
    __builtin_amdgcn_global_load_lds((const __attribute__((address_space(1))) void*)g,
                                     (__attribute__((address_space(3))) void*)l,
                                     16, 0, 0);
}

// ---------------- conversions ----------------
__global__ void convert_x_kernel(const float* __restrict__ x, unsigned short* __restrict__ xb) {
    int i = blockIdx.x * 256 + threadIdx.x;
    float4 v = ((const float4*)x)[i];
    uint2 o;
    o.x = (unsigned)f2bf(v.x) | ((unsigned)f2bf(v.y) << 16);
    o.y = (unsigned)f2bf(v.z) | ((unsigned)f2bf(v.w) << 16);
    *(uint2*)(xb + i * 4) = o;
}

__global__ void convert_w13_kernel(const float* __restrict__ w1, const float* __restrict__ w3,
                                   unsigned short* __restrict__ w1b, unsigned short* __restrict__ w3b) {
    const int HALF = (NE * HID * DIM) / 4;             // 5,591,040
    int i = blockIdx.x * 256 + threadIdx.x;
    const float* src; unsigned short* dst; int j;
    if (i < HALF) { src = w1; dst = w1b; j = i; }
    else          { src = w3; dst = w3b; j = i - HALF; }
    float4 v = ((const float4*)src)[j];
    uint2 o;
    o.x = (unsigned)f2bf(v.x) | ((unsigned)f2bf(v.y) << 16);
    o.y = (unsigned)f2bf(v.z) | ((unsigned)f2bf(v.w) << 16);
    *(uint2*)(dst + (size_t)j * 4) = o;
}

__global__ void convert_w2_kernel(const float* __restrict__ w2, unsigned short* __restrict__ w2b) {
    int i = blockIdx.x * 256 + threadIdx.x;            // 8192 rows * 688 chunks
    int r = i / 688;
    int c = (i - r * 688) * 4;
    const float* src = w2 + r * HID;
    unsigned short q[4];
#pragma unroll
    for (int j = 0; j < 4; ++j) {
        int col = c + j;
        q[j] = (col < HID) ? f2bf(src[col]) : (unsigned short)0;  // zero pad annihilates garbage h pad cols
    }
    uint2 o;
    o.x = (unsigned)q[0] | ((unsigned)q[1] << 16);
    o.y = (unsigned)q[2] | ((unsigned)q[3] << 16);
    *(uint2*)(w2b + (size_t)r * HPAD + c) = o;
}

// ---------------- router ----------------
__global__ void router_kernel(const float* __restrict__ x, const float* __restrict__ gw,
                              int* __restrict__ toks, int* __restrict__ meta,
                              float* __restrict__ tokw,
                              int* __restrict__ counts, float* __restrict__ psum) {
    __shared__ float gws[NE * DIM];        // 32 KB
    __shared__ float pblk[4][NE];
    int t = threadIdx.x;
    for (int i = t; i < NE * DIM; i += 256) gws[i] = gw[i];
    __syncthreads();

    int wv = t >> 6, lane = t & 63;
    int tok = blockIdx.x * 4 + wv;
    const float4* x4 = (const float4*)(x + (size_t)tok * DIM);

    float p[NE];
#pragma unroll
    for (int e = 0; e < NE; ++e) p[e] = 0.f;
#pragma unroll
    for (int c = 0; c < 4; ++c) {
        float4 xv = x4[c * 64 + lane];
#pragma unroll
        for (int e = 0; e < NE; ++e) {
            float4 gv = ((const float4*)(gws + e * DIM))[c * 64 + lane];
            p[e] += xv.x * gv.x + xv.y * gv.y + xv.z * gv.z + xv.w * gv.w;
        }
    }
#pragma unroll
    for (int e = 0; e < NE; ++e)
#pragma unroll
        for (int s = 32; s; s >>= 1) p[e] += __shfl_xor(p[e], s, 64);

    if (lane == 0) {
        float mx = p[0];
#pragma unroll
        for (int e = 1; e < NE; ++e) mx = fmaxf(mx, p[e]);
        float ex[NE], s = 0.f;
#pragma unroll
        for (int e = 0; e < NE; ++e) { ex[e] = __expf(p[e] - mx); s += ex[e]; }
        float inv = 1.f / s;
        int i1 = 0, i2 = 0; float v1 = -1.f, v2 = -1.f;
#pragma unroll
        for (int e = 0; e < NE; ++e) {
            float pe = ex[e] * inv;
            pblk[wv][e] = pe;
            if (pe > v1)      { v2 = v1; i2 = i1; v1 = pe; i1 = e; }
            else if (pe > v2) { v2 = pe; i2 = e; }
        }
        float wn = 1.f / (v1 + v2);
        int p1 = atomicAdd(&counts[i1], 1);
        toks[i1 * CAP + p1] = tok;
        meta[tok * 2]     = (i1 << 16) | p1;
        tokw[tok * 2]     = v1 * wn;
        int p2 = atomicAdd(&counts[i2], 1);
        toks[i2 * CAP + p2] = tok;
        meta[tok * 2 + 1] = (i2 << 16) | p2;
        tokw[tok * 2 + 1] = v2 * wn;
    }
    __syncthreads();
    if (t < NE) {
        float s = pblk[0][t] + pblk[1][t] + pblk[2][t] + pblk[3][t];
        atomicAdd(&psum[t], s);
    }
}

__global__ void finalize_kernel(const int* __restrict__ counts, int* __restrict__ offs,
                                const float* __restrict__ psum, float* __restrict__ aux_out) {
    if (threadIdx.x == 0) {
        int off = 0;
        for (int e = 0; e < NE; ++e) { offs[e] = off; off += counts[e]; }
        float s = 0.f;
        for (int e = 0; e < NE; ++e) {
            float d = psum[e] * (1.f / NTOK) - (1.f / NE);
            s += d * d;
        }
        aux_out[0] = 0.01f * s * (1.f / NE);
    }
}

// ---------------- stage-1: h = silu(x@w1^T) * (x@w3^T), gathered rows ----------------
// LDS layout: row-major 128 rows x 64 bf16, with XOR swizzle on the 8 16B-chunks
// per row: physical chunk p of row r holds global chunk p ^ (r&7). Staging fetches
// the swizzled chunk (LDS dest is forced to lane*16 by global_load_lds); fragment
// reads xor the chunk index. Rows now spread across all 8 bank groups -> 2-way
// aliasing only (free), vs 16-way before.
__global__ __launch_bounds__(256, 2) void gemm1_kernel(
    const unsigned short* __restrict__ xb,
    const unsigned short* __restrict__ w1b,
    const unsigned short* __restrict__ w3b,
    unsigned short* __restrict__ h,
    const int* __restrict__ counts, const int* __restrict__ offs,
    const int* __restrict__ toks) {
    const int e = blockIdx.z;
    const int M = counts[e];
    const int m0 = blockIdx.y * 128;
    if (m0 >= M) return;
    const int n0 = blockIdx.x * 128;

    __shared__ unsigned short As[128 * 64];
    __shared__ unsigned short B1s[128 * 64];
    __shared__ unsigned short B3s[128 * 64];

    const int t = threadIdx.x;
    const int rb = t >> 3;                          // staged row within 32-row group
    const int kc = ((t & 7) ^ (rb & 7)) * 8;        // swizzled k-chunk to fetch
    const int* tl = toks + e * CAP;
    int arow[4], brow[4];
#pragma unroll
    for (int i = 0; i < 4; ++i) {
        arow[i] = tl[min(m0 + rb + i * 32, M - 1)];
        brow[i] = min(n0 + rb + i * 32, HID - 1);
    }
    const unsigned short* w1e = w1b + (size_t)e * HID * DIM;
    const unsigned short* w3e = w3b + (size_t)e * HID * DIM;

    floatx4 acc1[4][4], acc3[4][4];
#pragma unroll
    for (int a = 0; a < 4; ++a)
#pragma unroll
        for (int b = 0; b < 4; ++b) {
            acc1[a][b] = (floatx4){0.f, 0.f, 0.f, 0.f};
            acc3[a][b] = (floatx4){0.f, 0.f, 0.f, 0.f};
        }

    const int wv = t >> 6, lane = t & 63;
    const int wm = (wv & 1) * 64, wn = (wv >> 1) * 64;
    const int lr = lane & 15, lq = lane >> 4;
    const int sw = lane & 7;                        // == row&7 for all fragment rows

    for (int k0 = 0; k0 < DIM; k0 += 64) {
#pragma unroll
        for (int i = 0; i < 4; ++i) {
            const int ldso = (i * 256 + t) * 8;
            gl2lds16(xb + (size_t)arow[i] * DIM + k0 + kc, &As[ldso]);
            gl2lds16(w1e + (size_t)brow[i] * DIM + k0 + kc, &B1s[ldso]);
            gl2lds16(w3e + (size_t)brow[i] * DIM + k0 + kc, &B3s[ldso]);
        }
        __syncthreads();
#pragma unroll
        for (int kk = 0; kk < 64; kk += 32) {
            const int pc = (((kk >> 3) + lq) ^ sw) * 8;   // physical chunk offset
            bf16x8 af[4];
#pragma unroll
            for (int mi = 0; mi < 4; ++mi)
                af[mi] = *(const bf16x8*)&As[(wm + mi * 16 + lr) * 64 + pc];
#pragma unroll
            for (int ni = 0; ni < 4; ++ni) {
                bf16x8 b1 = *(const bf16x8*)&B1s[(wn + ni * 16 + lr) * 64 + pc];
                bf16x8 b3 = *(const bf16x8*)&B3s[(wn + ni * 16 + lr) * 64 + pc];
#pragma unroll
                for (int mi = 0; mi < 4; ++mi) {
                    acc1[mi][ni] = __builtin_amdgcn_mfma_f32_16x16x32_bf16(af[mi], b1, acc1[mi][ni], 0, 0, 0);
                    acc3[mi][ni] = __builtin_amdgcn_mfma_f32_16x16x32_bf16(af[mi], b3, acc3[mi][ni], 0, 0, 0);
                }
            }
        }
        __syncthreads();
    }

    const int hb = offs[e];
#pragma unroll
    for (int mi = 0; mi < 4; ++mi) {
#pragma unroll
        for (int rg = 0; rg < 4; ++rg) {
            const int gm = m0 + wm + mi * 16 + lq * 4 + rg;
            if (gm >= M) continue;
            unsigned short* hrow = h + (size_t)(hb + gm) * HPAD;
#pragma unroll
            for (int ni = 0; ni < 4; ++ni) {
                const int col = n0 + wn + ni * 16 + lr;
                if (col >= HPAD) continue;
                float z1 = acc1[mi][ni][rg];
                float z3 = acc3[mi][ni][rg];
                float hv = z1 / (1.f + __expf(-z1)) * z3;   // silu(z1)*z3
                hrow[col] = f2bf(hv);
            }
        }
    }
}

// ---------------- stage-2: y[slot] = h[slot] @ w2^T (unweighted, no atomics) ----------------
__global__ __launch_bounds__(256, 2) void gemm2_kernel(
    const unsigned short* __restrict__ h,
    const unsigned short* __restrict__ w2b,
    float* __restrict__ y,
    const int* __restrict__ counts, const int* __restrict__ offs) {
    const int e = blockIdx.z;
    const int M = counts[e];
    const int m0 = blockIdx.y * 128;
    if (m0 >= M) return;
    const int n0 = blockIdx.x * 128;

    __shared__ unsigned short As[128 * 64];
    __shared__ unsigned short Bs[128 * 64];

    const int t = threadIdx.x;
    const int rb = t >> 3;
    const int kc = ((t & 7) ^ (rb & 7)) * 8;        // swizzled k-chunk
    const int hb = offs[e];
    int arow[4], brow[4];
#pragma unroll
    for (int i = 0; i < 4; ++i) {
        arow[i] = hb + min(m0 + rb + i * 32, M - 1);
        brow[i] = n0 + rb + i * 32;                 // always < 1024
    }
    const unsigned short* w2e = w2b + (size_t)e * DIM * HPAD;

    floatx4 acc[4][4];
#pragma unroll
    for (int a = 0; a < 4; ++a)
#pragma unroll
        for (int b = 0; b < 4; ++b) acc[a][b] = (floatx4){0.f, 0.f, 0.f, 0.f};

    const int wv = t >> 6, lane = t & 63;
    const int wm = (wv & 1) * 64, wn = (wv >> 1) * 64;
    const int lr = lane & 15, lq = lane >> 4;
    const int sw = lane & 7;

    for (int k0 = 0; k0 < HPAD; k0 += 64) {
#pragma unroll
        for (int i = 0; i < 4; ++i) {
            const int ldso = (i * 256 + t) * 8;
            gl2lds16(h + (size_t)arow[i] * HPAD + k0 + kc, &As[ldso]);
            gl2lds16(w2e + (size_t)brow[i] * HPAD + k0 + kc, &Bs[ldso]);
        }
        __syncthreads();
#pragma unroll
        for (int kk = 0; kk < 64; kk += 32) {
            const int pc = (((kk >> 3) + lq) ^ sw) * 8;
            bf16x8 af[4];
#pragma unroll
            for (int mi = 0; mi < 4; ++mi)
                af[mi] = *(const bf16x8*)&As[(wm + mi * 16 + lr) * 64 + pc];
#pragma unroll
            for (int ni = 0; ni < 4; ++ni) {
                bf16x8 bf = *(const bf16x8*)&Bs[(wn + ni * 16 + lr) * 64 + pc];
#pragma unroll
                for (int mi = 0; mi < 4; ++mi)
                    acc[mi][ni] = __builtin_amdgcn_mfma_f32_16x16x32_bf16(af[mi], bf, acc[mi][ni], 0, 0, 0);
            }
        }
        __syncthreads();
    }

#pragma unroll
    for (int mi = 0; mi < 4; ++mi) {
#pragma unroll
        for (int rg = 0; rg < 4; ++rg) {
            const int gm = m0 + wm + mi * 16 + lq * 4 + rg;
            if (gm >= M) continue;
            float* yrow = y + (size_t)(hb + gm) * DIM;
#pragma unroll
            for (int ni = 0; ni < 4; ++ni) {
                const int col = n0 + wn + ni * 16 + lr;
                yrow[col] = acc[mi][ni][rg];
            }
        }
    }
}

// ---------------- combine: out[tok] = w0*y[slot0] + w1*y[slot1] ----------------
__global__ void combine_kernel(const float* __restrict__ y,
                               const int* __restrict__ meta,
                               const float* __restrict__ tokw,
                               const int* __restrict__ offs,
                               float* __restrict__ out) {
    const int tok = blockIdx.x;
    const int t = threadIdx.x;                      // 256 threads x float4 = 1024
    const int m0 = meta[tok * 2], m1 = meta[tok * 2 + 1];
    const float w0 = tokw[tok * 2], w1 = tokw[tok * 2 + 1];
    const int r0 = offs[m0 >> 16] + (m0 & 0xffff);
    const int r1 = offs[m1 >> 16] + (m1 & 0xffff);
    float4 a = ((const float4*)(y + (size_t)r0 * DIM))[t];
    float4 b = ((const float4*)(y + (size_t)r1 * DIM))[t];
    float4 o;
    o.x = w0 * a.x + w1 * b.x;
    o.y = w0 * a.y + w1 * b.y;
    o.z = w0 * a.z + w1 * b.z;
    o.w = w0 * a.w + w1 * b.w;
    ((float4*)(out + (size_t)tok * DIM))[t] = o;
}

extern "C" void kernel_launch(void* const* d_in, const int* in_sizes, int n_in,
                              void* d_out, int out_size, void* d_ws, size_t ws_size,
                              hipStream_t stream) {
    const float* x  = (const float*)d_in[0];
    const float* gw = (const float*)d_in[1];
    const float* w1 = (const float*)d_in[2];
    const float* w2 = (const float*)d_in[3];   // dict order: w1, w2, w3
    const float* w3 = (const float*)d_in[4];
    float* out = (float*)d_out;

    char* ws = (char*)d_ws;
    size_t o = 0;
    auto alloc = [&](size_t bytes) -> void* {
        void* p = ws + o;
        o += (bytes + 255) & ~(size_t)255;
        return p;
    };
    unsigned short* xb   = (unsigned short*)alloc((size_t)NTOK * DIM * 2);
    unsigned short* w1b  = (unsigned short*)alloc((size_t)NE * HID * DIM * 2);
    unsigned short* w3b  = (unsigned short*)alloc((size_t)NE * HID * DIM * 2);
    unsigned short* w2b  = (unsigned short*)alloc((size_t)NE * DIM * HPAD * 2);
    unsigned short* hbuf = (unsigned short*)alloc((size_t)2 * NTOK * HPAD * 2);
    int*   toks   = (int*)alloc((size_t)NE * CAP * 4);
    int*   meta   = (int*)alloc((size_t)NTOK * 2 * 4);
    float* tokw   = (float*)alloc((size_t)NTOK * 2 * 4);
    int*   counts = (int*)alloc(256);
    float* psum   = (float*)alloc(256);
    int*   offs   = (int*)alloc(256);
    if (o > ws_size) return;
    // y (16384 x 1024 fp32, 67 MB) aliases the dead w1b+w3b region (89.4 MB):
    // w1b/w3b are consumed by gemm1, which completes before gemm2 writes y
    // (stream-ordered). Saves 67 MB of workspace.
    float* ybuf = (float*)w1b;

    hipMemsetAsync(counts, 0, 256, stream);
    hipMemsetAsync(psum, 0, 256, stream);

    convert_x_kernel<<<8192, 256, 0, stream>>>(x, xb);
    convert_w13_kernel<<<43680, 256, 0, stream>>>(w1, w3, w1b, w3b);
    convert_w2_kernel<<<22016, 256, 0, stream>>>(w2, w2b);
    router_kernel<<<2048, 256, 0, stream>>>(x, gw, toks, meta, tokw, counts, psum);
    finalize_kernel<<<1, 64, 0, stream>>>(counts, offs, psum, out + (size_t)NTOK * DIM);
    gemm1_kernel<<<dim3(22, 64, 8), 256, 0, stream>>>(xb, w1b, w3b, hbuf, counts, offs, toks);
    gemm2_kernel<<<dim3(8, 64, 8), 256, 0, stream>>>(hbuf, w2b, ybuf, counts, offs);
    combine_kernel<<<NTOK, 256, 0, stream>>>(ybuf, meta, tokw, offs, out);
}